// Round 7
// baseline (856.805 us; speedup 1.0000x reference)
//
#include <hip/hip_runtime.h>

#define GRID   2048
#define BLOCK  256
#define BATCH  16384
#define NJ     25
#define DEPTH  256
#define ITERS  (BATCH / GRID)   // 8

typedef short s16x8 __attribute__((ext_vector_type(8)));
typedef short s16x4 __attribute__((ext_vector_type(4)));
typedef float f32x4 __attribute__((ext_vector_type(4)));

// fp32 -> bf16 round-to-nearest-even
__device__ __forceinline__ short f2bf(float f) {
  union { float f; unsigned u; } c; c.f = f;
  unsigned r = (c.u + 0x7FFFu + ((c.u >> 16) & 1u)) >> 16;
  return (short)r;
}

#define MFMA(a, b, c) __builtin_amdgcn_mfma_f32_16x16x32_bf16((a), (b), (c), 0, 0, 0)

// ---- prep: W (fp32, [256][256]) -> d_ws as bf16 MFMA B-fragments ----
// layout: elem t = ((wv*8 + ks)*4 + td)*64 + lane  holds
//   W[ks*32 + quad*8 + j][wv*64 + td*16 + l16], j=0..7   (s16x8)
__global__ __launch_bounds__(256)
void prep_w(const float* __restrict__ w, short* __restrict__ ws) {
  const int t    = blockIdx.x * 256 + threadIdx.x;   // 0..8191
  const int lane = t & 63;
  const int td   = (t >> 6) & 3;
  const int ks   = (t >> 8) & 7;
  const int wvv  = t >> 11;
  const int quad = lane >> 4, l16 = lane & 15;
  const float* wp = w + (size_t)(ks * 32 + quad * 8) * DEPTH + wvv * 64 + td * 16 + l16;
  s16x8 h;
#pragma unroll
  for (int j = 0; j < 8; ++j) h[j] = f2bf(wp[(size_t)j * DEPTH]);
  *(s16x8*)(ws + (size_t)t * 8) = h;
}

// ---- main: r4 skeleton, W streamed from L2-resident frag image ----
// 4 waves x 64 cols, single As (chunk-swizzled), 2 barriers/iter, element
// prefetch in regs across the K loop, stores issued last (drain aged at next
// barA). wf NOT resident: per-K-step b128 loads from d_ws, even/odd 1-deep
// pipeline. Regs ~110-125 -> 4 blocks/CU (the whole point of this round).
__global__ __launch_bounds__(BLOCK, 4)
void geo_gcn_fused(const float* __restrict__ x,
                   const short* __restrict__ wfrag,
                   float* __restrict__ out)
{
  __shared__ short As[32][256];     // 16384 B, chunk-swizzled
  __shared__ short Ps[32][40];      //  2560 B
  __shared__ float S3[32][36];      //  4608 B
  __shared__ short Yt[4][64][32];   // 16384 B, swizzled  -> 39936 B total (4/CU)

  const int tid  = threadIdx.x;
  const int wv   = tid >> 6;        // 0..3, owns cols [64*wv, 64*wv+64)
  const int lane = tid & 63;
  const int quad = lane >> 4;
  const int l16  = lane & 15;

  // per-lane base into the W-fragment image: index (ks,td) -> wsv[ks*256 + td*64]
  const s16x8* wsv = (const s16x8*)wfrag + (size_t)wv * 2048 + lane;

  const int tm_s = wv >> 1;         // s3 tile (tm_s, tn_s) per wave
  const int tn_s = wv & 1;
  const int srow = tid >> 3;        // staging row 0..31 (rows >= NJ stay zero)
  const int sq   = tid & 7;         // 8 threads/row, 32 floats each
  const int ssw  = (sq ^ (srow & 7)) * 8;   // swizzled chunk offset (shorts)

  const float* xb = x + (size_t)srow * BATCH * DEPTH + sq * 8;

  // ---- prologue: stage element blockIdx.x into As ----
  {
    const float* xp = xb + (size_t)blockIdx.x * DEPTH;
#pragma unroll
    for (int c = 0; c < 4; ++c) {
      float4 c0 = make_float4(0.f, 0.f, 0.f, 0.f), c1 = c0;
      if (srow < NJ) {
        c0 = *(const float4*)(xp + c * 64);
        c1 = *(const float4*)(xp + c * 64 + 4);
      }
      s16x8 h;
      h[0]=f2bf(c0.x); h[1]=f2bf(c0.y); h[2]=f2bf(c0.z); h[3]=f2bf(c0.w);
      h[4]=f2bf(c1.x); h[5]=f2bf(c1.y); h[6]=f2bf(c1.z); h[7]=f2bf(c1.w);
      *(s16x8*)&As[srow][ssw + c * 64] = h;
    }
  }
  __syncthreads();

  for (int ib = 0; ib < ITERS; ++ib) {
    const int b = blockIdx.x + GRID * ib;

    // ---- issue NEXT element's loads; consumed after barA (aged by K loop) ----
    float4 nf[8];
#pragma unroll
    for (int i = 0; i < 8; ++i) nf[i] = make_float4(0.f, 0.f, 0.f, 0.f);
    if ((ib + 1 < ITERS) && (srow < NJ)) {
      const float* xp = xb + (size_t)(b + GRID) * DEPTH;
#pragma unroll
      for (int c = 0; c < 4; ++c) {
        nf[2 * c]     = *(const float4*)(xp + c * 64);
        nf[2 * c + 1] = *(const float4*)(xp + c * 64 + 4);
      }
    }

    f32x4 sacc = (f32x4){0.f, 0.f, 0.f, 0.f};
    f32x4 yacc[2][4];
#pragma unroll
    for (int i = 0; i < 2; ++i)
#pragma unroll
      for (int j = 0; j < 4; ++j) yacc[i][j] = (f32x4){0.f, 0.f, 0.f, 0.f};

    // ---- K loop: 8 x K=32; wf streamed (even/odd 1-deep pipeline) ----
    s16x8 wE[4], wO[4];
#pragma unroll
    for (int td = 0; td < 4; ++td) {
      wE[td] = wsv[td * 64];          // ks = 0
      wO[td] = wsv[256 + td * 64];    // ks = 1
    }
#pragma unroll 1
    for (int kp = 0; kp < 4; ++kp) {
      {
        const int ks = 2 * kp;
        const int co = (((ks * 4 + quad) ^ (l16 & 7)) << 3);
        s16x8 a0 = *(const s16x8*)&As[l16][co];
        s16x8 a1 = *(const s16x8*)&As[16 + l16][co];
        sacc = MFMA(tm_s ? a1 : a0, tn_s ? a1 : a0, sacc);
#pragma unroll
        for (int td = 0; td < 4; ++td) {
          yacc[0][td] = MFMA(a0, wE[td], yacc[0][td]);
          yacc[1][td] = MFMA(a1, wE[td], yacc[1][td]);
        }
        if (kp < 3) {
          const int kn = (ks + 2) * 256;
#pragma unroll
          for (int td = 0; td < 4; ++td) wE[td] = wsv[kn + td * 64];
        }
      }
      {
        const int ks = 2 * kp + 1;
        const int co = (((ks * 4 + quad) ^ (l16 & 7)) << 3);
        s16x8 a0 = *(const s16x8*)&As[l16][co];
        s16x8 a1 = *(const s16x8*)&As[16 + l16][co];
        sacc = MFMA(tm_s ? a1 : a0, tn_s ? a1 : a0, sacc);
#pragma unroll
        for (int td = 0; td < 4; ++td) {
          yacc[0][td] = MFMA(a0, wO[td], yacc[0][td]);
          yacc[1][td] = MFMA(a1, wO[td], yacc[1][td]);
        }
        if (kp < 3) {
          const int kn = (ks + 2) * 256;
#pragma unroll
          for (int td = 0; td < 4; ++td) wO[td] = wsv[kn + td * 64];
        }
      }
    }

    // ---- s3 -> LDS (pitch 36: 2-way max) ----
#pragma unroll
    for (int r = 0; r < 4; ++r)
      S3[tm_s * 16 + quad * 4 + r][tn_s * 16 + l16] = sacc[r];
    __syncthreads();   // barA: all As reads done; prefetch + prev stores aged

    // ---- stage NEXT element into As (reads complete at barA) ----
    if (ib + 1 < ITERS) {
#pragma unroll
      for (int c = 0; c < 4; ++c) {
        s16x8 h;
        h[0]=f2bf(nf[2*c].x);   h[1]=f2bf(nf[2*c].y);
        h[2]=f2bf(nf[2*c].z);   h[3]=f2bf(nf[2*c].w);
        h[4]=f2bf(nf[2*c+1].x); h[5]=f2bf(nf[2*c+1].y);
        h[6]=f2bf(nf[2*c+1].z); h[7]=f2bf(nf[2*c+1].w);
        *(s16x8*)&As[srow][ssw + c * 64] = h;
      }
    }

    // ---- wave-parallel softmax: 8 lanes/row over 32 rows ----
    {
      const int row = tid >> 3, c8 = tid & 7;
      float v[4]; float mx = -3.0e38f;
#pragma unroll
      for (int i = 0; i < 4; ++i) {
        const int j = c8 + 8 * i;
        v[i] = (j < NJ) ? S3[row][j] : -3.0e38f;
        mx = fmaxf(mx, v[i]);
      }
      mx = fmaxf(mx, __shfl_xor(mx, 1));
      mx = fmaxf(mx, __shfl_xor(mx, 2));
      mx = fmaxf(mx, __shfl_xor(mx, 4));
      float e[4]; float sum = 0.f;
#pragma unroll
      for (int i = 0; i < 4; ++i) {
        const int j = c8 + 8 * i;
        e[i] = (j < NJ) ? __expf(v[i] - mx) : 0.f;
        sum += e[i];
      }
      sum += __shfl_xor(sum, 1);
      sum += __shfl_xor(sum, 2);
      sum += __shfl_xor(sum, 4);
      const float rinv = 1.0f / sum;
#pragma unroll
      for (int i = 0; i < 4; ++i)
        Ps[row][c8 + 8 * i] = f2bf(e[i] * rinv);   // cols >= NJ get exact 0
    }
    __syncthreads();   // barB: LDS-only drain (cheap)

    // ---- Y (C-layout) -> Yt, phys_chunk = logical ^ ((d>>1)&3) ----
#pragma unroll
    for (int tm = 0; tm < 2; ++tm)
#pragma unroll
      for (int td = 0; td < 4; ++td) {
        s16x4 hy;
#pragma unroll
        for (int r = 0; r < 4; ++r) hy[r] = f2bf(yacc[tm][td][r]);
        const int pc = (tm * 2 + (quad >> 1)) ^ ((l16 >> 1) & 3);
        *(s16x4*)&Yt[wv][td * 16 + l16][pc * 8 + (quad & 1) * 4] = hy;
      }
    // same-wave DS ordering: Yt writes precede this wave's Yt reads

    // ---- out_strip = P @ Y_strip; stores issued LAST, no trailing barrier ----
    s16x8 pf0 = *(const s16x8*)&Ps[l16][quad * 8];
    s16x8 pf1 = *(const s16x8*)&Ps[16 + l16][quad * 8];
    const f32x4 z4 = (f32x4){0.f, 0.f, 0.f, 0.f};
    float* ob = out + (size_t)b * NJ * DEPTH + wv * 64 + l16;
#pragma unroll
    for (int td = 0; td < 4; ++td) {
      const int pr = quad ^ ((l16 >> 1) & 3);    // conflict-free swizzled read
      s16x8 yb = *(const s16x8*)&Yt[wv][td * 16 + l16][pr * 8];
      f32x4 o0 = MFMA(pf0, yb, z4);
      f32x4 o1 = MFMA(pf1, yb, z4);
#pragma unroll
      for (int r = 0; r < 4; ++r) {
        ob[(size_t)(quad * 4 + r) * DEPTH + td * 16] = o0[r];   // rows 0..15
        const int nr = 16 + quad * 4 + r;                       // rows 16..24
        if (nr < NJ) ob[(size_t)nr * DEPTH + td * 16] = o1[r];
      }
    }
    // next iter's As reads gated by barB; stores drain at next iter's barA.
  }
}

// ---- fallback (verbatim round-4 kernel): used only if ws_size < 128 KB ----
__global__ __launch_bounds__(BLOCK, 2)
void geo_gcn_fused_fb(const float* __restrict__ x,
                      const float* __restrict__ w,
                      float* __restrict__ out)
{
  __shared__ short As[32][256];
  __shared__ short Ps[32][40];
  __shared__ float S3[32][36];
  __shared__ short Yt[4][64][32];

  const int tid  = threadIdx.x;
  const int wv   = tid >> 6;
  const int lane = tid & 63;
  const int quad = lane >> 4;
  const int l16  = lane & 15;

  s16x8 wf[8][4];
  {
    const int ncol = wv * 64 + l16;
#pragma unroll
    for (int ks = 0; ks < 8; ++ks)
#pragma unroll
      for (int td = 0; td < 4; ++td) {
        const float* wp = w + (size_t)(ks * 32 + quad * 8) * DEPTH + ncol + td * 16;
#pragma unroll
        for (int j = 0; j < 8; ++j)
          wf[ks][td][j] = f2bf(wp[(size_t)j * DEPTH]);
      }
  }

  const int tm_s = wv >> 1;
  const int tn_s = wv & 1;
  const int srow = tid >> 3;
  const int sq   = tid & 7;
  const int ssw  = (sq ^ (srow & 7)) * 8;
  const int FITERS = BATCH / GRID;

  const float* xb = x + (size_t)srow * BATCH * DEPTH + sq * 8;
  {
    const float* xp = xb + (size_t)blockIdx.x * DEPTH;
#pragma unroll
    for (int c = 0; c < 4; ++c) {
      float4 c0 = make_float4(0.f, 0.f, 0.f, 0.f), c1 = c0;
      if (srow < NJ) {
        c0 = *(const float4*)(xp + c * 64);
        c1 = *(const float4*)(xp + c * 64 + 4);
      }
      s16x8 h;
      h[0]=f2bf(c0.x); h[1]=f2bf(c0.y); h[2]=f2bf(c0.z); h[3]=f2bf(c0.w);
      h[4]=f2bf(c1.x); h[5]=f2bf(c1.y); h[6]=f2bf(c1.z); h[7]=f2bf(c1.w);
      *(s16x8*)&As[srow][ssw + c * 64] = h;
    }
  }
  __syncthreads();

  for (int ib = 0; ib < FITERS; ++ib) {
    const int b = blockIdx.x + GRID * ib;
    float4 nf[8];
#pragma unroll
    for (int i = 0; i < 8; ++i) nf[i] = make_float4(0.f, 0.f, 0.f, 0.f);
    if ((ib + 1 < FITERS) && (srow < NJ)) {
      const float* xp = xb + (size_t)(b + GRID) * DEPTH;
#pragma unroll
      for (int c = 0; c < 4; ++c) {
        nf[2 * c]     = *(const float4*)(xp + c * 64);
        nf[2 * c + 1] = *(const float4*)(xp + c * 64 + 4);
      }
    }
    f32x4 sacc = (f32x4){0.f, 0.f, 0.f, 0.f};
    f32x4 yacc[2][4];
#pragma unroll
    for (int i = 0; i < 2; ++i)
#pragma unroll
      for (int j = 0; j < 4; ++j) yacc[i][j] = (f32x4){0.f, 0.f, 0.f, 0.f};
#pragma unroll
    for (int ks = 0; ks < 8; ++ks) {
      const int co = (((ks * 4 + quad) ^ (l16 & 7)) << 3);
      s16x8 a0 = *(const s16x8*)&As[l16][co];
      s16x8 a1 = *(const s16x8*)&As[16 + l16][co];
      sacc = MFMA(tm_s ? a1 : a0, tn_s ? a1 : a0, sacc);
#pragma unroll
      for (int td = 0; td < 4; ++td) {
        yacc[0][td] = MFMA(a0, wf[ks][td], yacc[0][td]);
        yacc[1][td] = MFMA(a1, wf[ks][td], yacc[1][td]);
      }
    }
#pragma unroll
    for (int r = 0; r < 4; ++r)
      S3[tm_s * 16 + quad * 4 + r][tn_s * 16 + l16] = sacc[r];
    __syncthreads();
    if (ib + 1 < FITERS) {
#pragma unroll
      for (int c = 0; c < 4; ++c) {
        s16x8 h;
        h[0]=f2bf(nf[2*c].x);   h[1]=f2bf(nf[2*c].y);
        h[2]=f2bf(nf[2*c].z);   h[3]=f2bf(nf[2*c].w);
        h[4]=f2bf(nf[2*c+1].x); h[5]=f2bf(nf[2*c+1].y);
        h[6]=f2bf(nf[2*c+1].z); h[7]=f2bf(nf[2*c+1].w);
        *(s16x8*)&As[srow][ssw + c * 64] = h;
      }
    }
    {
      const int row = tid >> 3, c8 = tid & 7;
      float v[4]; float mx = -3.0e38f;
#pragma unroll
      for (int i = 0; i < 4; ++i) {
        const int j = c8 + 8 * i;
        v[i] = (j < NJ) ? S3[row][j] : -3.0e38f;
        mx = fmaxf(mx, v[i]);
      }
      mx = fmaxf(mx, __shfl_xor(mx, 1));
      mx = fmaxf(mx, __shfl_xor(mx, 2));
      mx = fmaxf(mx, __shfl_xor(mx, 4));
      float e[4]; float sum = 0.f;
#pragma unroll
      for (int i = 0; i < 4; ++i) {
        const int j = c8 + 8 * i;
        e[i] = (j < NJ) ? __expf(v[i] - mx) : 0.f;
        sum += e[i];
      }
      sum += __shfl_xor(sum, 1);
      sum += __shfl_xor(sum, 2);
      sum += __shfl_xor(sum, 4);
      const float rinv = 1.0f / sum;
#pragma unroll
      for (int i = 0; i < 4; ++i)
        Ps[row][c8 + 8 * i] = f2bf(e[i] * rinv);
    }
    __syncthreads();
#pragma unroll
    for (int tm = 0; tm < 2; ++tm)
#pragma unroll
      for (int td = 0; td < 4; ++td) {
        s16x4 hy;
#pragma unroll
        for (int r = 0; r < 4; ++r) hy[r] = f2bf(yacc[tm][td][r]);
        const int pc = (tm * 2 + (quad >> 1)) ^ ((l16 >> 1) & 3);
        *(s16x4*)&Yt[wv][td * 16 + l16][pc * 8 + (quad & 1) * 4] = hy;
      }
    s16x8 pf0 = *(const s16x8*)&Ps[l16][quad * 8];
    s16x8 pf1 = *(const s16x8*)&Ps[16 + l16][quad * 8];
    const f32x4 z4 = (f32x4){0.f, 0.f, 0.f, 0.f};
    float* ob = out + (size_t)b * NJ * DEPTH + wv * 64 + l16;
#pragma unroll
    for (int td = 0; td < 4; ++td) {
      const int pr = quad ^ ((l16 >> 1) & 3);
      s16x8 yb = *(const s16x8*)&Yt[wv][td * 16 + l16][pr * 8];
      f32x4 o0 = MFMA(pf0, yb, z4);
      f32x4 o1 = MFMA(pf1, yb, z4);
#pragma unroll
      for (int r = 0; r < 4; ++r) {
        ob[(size_t)(quad * 4 + r) * DEPTH + td * 16] = o0[r];
        const int nr = 16 + quad * 4 + r;
        if (nr < NJ) ob[(size_t)nr * DEPTH + td * 16] = o1[r];
      }
    }
  }
}

extern "C" void kernel_launch(void* const* d_in, const int* in_sizes, int n_in,
                              void* d_out, int out_size, void* d_ws, size_t ws_size,
                              hipStream_t stream) {
  (void)in_sizes; (void)n_in; (void)out_size;
  const float* x = (const float*)d_in[0];
  const float* w = (const float*)d_in[1];
  float* out = (float*)d_out;
  if (d_ws != nullptr && ws_size >= 131072) {
    prep_w<<<dim3(32), dim3(256), 0, stream>>>(w, (short*)d_ws);
    geo_gcn_fused<<<dim3(GRID), dim3(BLOCK), 0, stream>>>(x, (const short*)d_ws, out);
  } else {
    geo_gcn_fused_fb<<<dim3(GRID), dim3(BLOCK), 0, stream>>>(x, w, out);
  }
}

// Round 8
// 740.495 us; speedup vs baseline: 1.1571x; 1.1571x over previous
//
#include <hip/hip_runtime.h>

#define GRID   256
#define BLOCK  1024
#define BATCH  16384
#define NJ     25
#define DEPTH  256
#define WPB    16                // waves per block
#define TOTW   (GRID * WPB)      // 4096 waves total
#define ELEMS  (BATCH / TOTW)    // 4 elements per wave

typedef short s16x8 __attribute__((ext_vector_type(8)));
typedef float f32x4 __attribute__((ext_vector_type(4)));

// fp32 -> bf16 round-to-nearest-even
__device__ __forceinline__ short f2bf(float f) {
  union { float f; unsigned u; } c; c.f = f;
  unsigned r = (c.u + 0x7FFFu + ((c.u >> 16) & 1u)) >> 16;
  return (short)r;
}
// pack two floats as bf16x2 dword (lo = first element)
__device__ __forceinline__ unsigned pk2(float lo, float hi) {
  return ((unsigned)(unsigned short)f2bf(hi) << 16) |
         (unsigned)(unsigned short)f2bf(lo);
}

#define MFMA(a, b, c) __builtin_amdgcn_mfma_f32_16x16x32_bf16((a), (b), (c), 0, 0, 0)

// Wave-autonomous (r6's verified math) at 4 waves/SIMD:
//  - one 1024-thread block per CU; W staged ONCE as a linear bf16 fragment
//    image in LDS (128 KB exactly, no padding): entry e=(td*8+ks)*64+lane
//    holds s16x8 { W[ks*32 + quad*8 + j][td*16 + l16] }.
//    td-loop reads are lane-linear b128 -> 2 lanes/bank max (free).
//  - 16 waves/CU, each wave fully independent, ZERO barriers after prologue.
//  - s3 = A.A^T is symmetric -> softmax wave-local (shfl_xor 16/32 only);
//    P (A-frag) and Y (B-frag) built in-register via the 8-shfl web.
__global__ __launch_bounds__(BLOCK)
void geo_gcn_fused(const float* __restrict__ x,
                   const float* __restrict__ w,
                   float* __restrict__ out)
{
  __shared__ s16x8 Wfr[8192];   // 131072 B

  const int tid  = threadIdx.x;
  const int wv   = tid >> 6;
  const int lane = tid & 63;
  const int q    = lane >> 4;
  const int l16  = lane & 15;

  // ---- prologue: build the W fragment image (each thread: 8 entries) ----
#pragma unroll
  for (int it = 0; it < 8; ++it) {
    const int e    = tid + BLOCK * it;    // 0..8191
    const int el   = e & 63;
    const int eks  = (e >> 6) & 7;
    const int etd  = e >> 9;
    const int eq   = el >> 4, el16 = el & 15;
    const float* wp = w + (size_t)(eks * 32 + eq * 8) * DEPTH + etd * 16 + el16;
    s16x8 h;
#pragma unroll
    for (int j = 0; j < 8; ++j) h[j] = f2bf(wp[(size_t)j * DEPTH]);
    Wfr[e] = h;
  }
  __syncthreads();   // the ONLY barrier

  const int gw = blockIdx.x * WPB + wv;                              // 0..4095
  const float* xr0 = x + (size_t)l16 * BATCH * DEPTH + q * 8;        // row l16
  const float* xr1 = x + (size_t)(16 + l16) * BATCH * DEPTH + q * 8; // row 16+l16
  const bool  r1ok = (l16 < NJ - 16);       // row 16+l16 valid (l16 < 9)
  const int   sA   = ((q & 1) << 5) + l16;  // shfl src lanes for the webs
  const int   sB   = sA + 16;
  const bool  lo32 = (lane < 32);           // tm select: q>>1 == 0
  const f32x4 z4   = (f32x4){0.f, 0.f, 0.f, 0.f};
  const s16x8 z8   = (s16x8){0, 0, 0, 0, 0, 0, 0, 0};

  for (int i = 0; i < ELEMS; ++i) {
    const int b = gw + TOTW * i;
    const size_t boff = (size_t)b * DEPTH;

    // ---- A-frags straight from global ----
    s16x8 af0[8], af1[8];
#pragma unroll
    for (int ks = 0; ks < 8; ++ks) {
      float4 c0 = *(const float4*)(xr0 + boff + ks * 32);
      float4 c1 = *(const float4*)(xr0 + boff + ks * 32 + 4);
      s16x8 h;
      h[0]=f2bf(c0.x); h[1]=f2bf(c0.y); h[2]=f2bf(c0.z); h[3]=f2bf(c0.w);
      h[4]=f2bf(c1.x); h[5]=f2bf(c1.y); h[6]=f2bf(c1.z); h[7]=f2bf(c1.w);
      af0[ks] = h;
      s16x8 g = z8;
      if (r1ok) {
        float4 d0 = *(const float4*)(xr1 + boff + ks * 32);
        float4 d1 = *(const float4*)(xr1 + boff + ks * 32 + 4);
        g[0]=f2bf(d0.x); g[1]=f2bf(d0.y); g[2]=f2bf(d0.z); g[3]=f2bf(d0.w);
        g[4]=f2bf(d1.x); g[5]=f2bf(d1.y); g[6]=f2bf(d1.z); g[7]=f2bf(d1.w);
      }
      af1[ks] = g;     // rows >= 25 stay zero
    }

    // ---- s3 = A.A^T, all 4 16x16 tiles ----
    f32x4 s00 = z4, s01 = z4, s10 = z4, s11 = z4;
#pragma unroll
    for (int ks = 0; ks < 8; ++ks) {
      s00 = MFMA(af0[ks], af0[ks], s00);
      s01 = MFMA(af0[ks], af1[ks], s01);
      s10 = MFMA(af1[ks], af0[ks], s10);
      s11 = MFMA(af1[ks], af1[ks], s11);
    }

    // ---- wave-local softmax via symmetry ----
    unsigned pd0[2][2], pd1[2][2];   // [mt][rp] packed bf16x2
    {
      float m0 = fmaxf(fmaxf(s00[0], s00[1]), fmaxf(s00[2], s00[3]));
      float m1 = fmaxf(fmaxf(s01[0], s01[1]), fmaxf(s01[2], s01[3]));
#pragma unroll
      for (int r = 0; r < 4; ++r) {
        if (4 * q + r < 9) {           // col 16+4q+r < 25
          m0 = fmaxf(m0, s10[r]);
          m1 = fmaxf(m1, s11[r]);
        }
      }
      m0 = fmaxf(m0, __shfl_xor(m0, 16)); m0 = fmaxf(m0, __shfl_xor(m0, 32));
      m1 = fmaxf(m1, __shfl_xor(m1, 16)); m1 = fmaxf(m1, __shfl_xor(m1, 32));
      float e00[4], e01[4], e10[4], e11[4];
      float t0 = 0.f, t1 = 0.f;
#pragma unroll
      for (int r = 0; r < 4; ++r) {
        const bool v = (4 * q + r) < 9;
        e00[r] = __expf(s00[r] - m0);
        e10[r] = __expf(s01[r] - m1);
        e01[r] = v ? __expf(s10[r] - m0) : 0.f;
        e11[r] = v ? __expf(s11[r] - m1) : 0.f;
        t0 += e00[r] + e01[r];
        t1 += e10[r] + e11[r];
      }
      t0 += __shfl_xor(t0, 16); t0 += __shfl_xor(t0, 32);
      t1 += __shfl_xor(t1, 16); t1 += __shfl_xor(t1, 32);
      const float i0 = 1.0f / t0, i1 = 1.0f / t1;
      pd0[0][0] = pk2(e00[0] * i0, e00[1] * i0);
      pd0[0][1] = pk2(e00[2] * i0, e00[3] * i0);
      pd0[1][0] = pk2(e01[0] * i0, e01[1] * i0);
      pd0[1][1] = pk2(e01[2] * i0, e01[3] * i0);
      pd1[0][0] = pk2(e10[0] * i1, e10[1] * i1);
      pd1[0][1] = pk2(e10[2] * i1, e10[3] * i1);
      pd1[1][0] = pk2(e11[0] * i1, e11[1] * i1);
      pd1[1][1] = pk2(e11[2] * i1, e11[3] * i1);
    }

    // ---- P A-frags via the shfl web ----
    s16x8 pf0, pf1;
    {
      union { unsigned u[4]; s16x8 v; } p0, p1;
      int a, c;
      a = __shfl((int)pd0[0][0], sA); c = __shfl((int)pd0[1][0], sA); p0.u[0] = lo32 ? a : c;
      a = __shfl((int)pd0[0][1], sA); c = __shfl((int)pd0[1][1], sA); p0.u[1] = lo32 ? a : c;
      a = __shfl((int)pd0[0][0], sB); c = __shfl((int)pd0[1][0], sB); p0.u[2] = lo32 ? a : c;
      a = __shfl((int)pd0[0][1], sB); c = __shfl((int)pd0[1][1], sB); p0.u[3] = lo32 ? a : c;
      a = __shfl((int)pd1[0][0], sA); c = __shfl((int)pd1[1][0], sA); p1.u[0] = lo32 ? a : c;
      a = __shfl((int)pd1[0][1], sA); c = __shfl((int)pd1[1][1], sA); p1.u[1] = lo32 ? a : c;
      a = __shfl((int)pd1[0][0], sB); c = __shfl((int)pd1[1][0], sB); p1.u[2] = lo32 ? a : c;
      a = __shfl((int)pd1[0][1], sB); c = __shfl((int)pd1[1][1], sB); p1.u[3] = lo32 ? a : c;
      pf0 = p0.v;   // P[m = l16][k = 8q .. 8q+7]
      pf1 = p1.v;   // P[m = 16+l16][k = 8q .. 8q+7]
    }

    // ---- td loop: Y tiles -> in-reg transpose -> PV -> store ----
    float* ob = out + (size_t)b * NJ * DEPTH;
#pragma unroll 2
    for (int td = 0; td < 16; ++td) {
      const s16x8* wfp = &Wfr[td * 512 + lane];
      f32x4 y0 = z4, y1 = z4;
#pragma unroll
      for (int ks = 0; ks < 8; ++ks) {
        const s16x8 wb = wfp[ks * 64];   // W[ks*32+q*8+j][16td+l16]
        y0 = MFMA(af0[ks], wb, y0);      // Y rows 0..15
        y1 = MFMA(af1[ks], wb, y1);      // Y rows 16..31 (>=25 are zero)
      }
      const unsigned a0 = pk2(y0[0], y0[1]), a1 = pk2(y0[2], y0[3]);
      const unsigned b0 = pk2(y1[0], y1[1]), b1 = pk2(y1[2], y1[3]);
      union { unsigned u[4]; s16x8 v; } yu;
      {
        int u0, u1;
        u0 = __shfl((int)a0, sA); u1 = __shfl((int)b0, sA); yu.u[0] = lo32 ? u0 : u1;
        u0 = __shfl((int)a1, sA); u1 = __shfl((int)b1, sA); yu.u[1] = lo32 ? u0 : u1;
        u0 = __shfl((int)a0, sB); u1 = __shfl((int)b0, sB); yu.u[2] = lo32 ? u0 : u1;
        u0 = __shfl((int)a1, sB); u1 = __shfl((int)b1, sB); yu.u[3] = lo32 ? u0 : u1;
      }
      // yu.v = B-frag: Y[k = 8q+j][n = 16td + l16]
      f32x4 o0 = MFMA(pf0, yu.v, z4);
      f32x4 o1 = MFMA(pf1, yu.v, z4);
      float* op = ob + 16 * td + l16;
#pragma unroll
      for (int r = 0; r < 4; ++r) {
        op[(size_t)(4 * q + r) * DEPTH] = o0[r];   // rows 0..15
        const int nr = 16 + 4 * q + r;             // rows 16..24 only
        if (nr < NJ) op[(size_t)nr * DEPTH] = o1[r];
      }
    }
  }
}

extern "C" void kernel_launch(void* const* d_in, const int* in_sizes, int n_in,
                              void* d_out, int out_size, void* d_ws, size_t ws_size,
                              hipStream_t stream) {
  (void)in_sizes; (void)n_in; (void)out_size; (void)d_ws; (void)ws_size;
  const float* x = (const float*)d_in[0];
  const float* w = (const float*)d_in[1];
  float* out = (float*)d_out;
  geo_gcn_fused<<<dim3(GRID), dim3(BLOCK), 0, stream>>>(x, w, out);
}

// Round 9
// 716.323 us; speedup vs baseline: 1.1961x; 1.0337x over previous
//
#include <hip/hip_runtime.h>

#define GRID   1024
#define BLOCK  256
#define BATCH  16384
#define NJ     25
#define DEPTH  256
#define ITERS  (BATCH / GRID)   // 16

typedef short s16x8 __attribute__((ext_vector_type(8)));
typedef short s16x4 __attribute__((ext_vector_type(4)));
typedef float f32x4 __attribute__((ext_vector_type(4)));

// fp32 -> bf16 round-to-nearest-even
__device__ __forceinline__ short f2bf(float f) {
  union { float f; unsigned u; } c; c.f = f;
  unsigned r = (c.u + 0x7FFFu + ((c.u >> 16) & 1u)) >> 16;
  return (short)r;
}

#define MFMA(a, b, c) __builtin_amdgcn_mfma_f32_16x16x32_bf16((a), (b), (c), 0, 0, 0)

// async 16B global -> LDS (no dest VGPRs; lane i writes lds + 16*i)
__device__ __forceinline__ void dma16(const float* g, float* l) {
  __builtin_amdgcn_global_load_lds(
      (const __attribute__((address_space(1))) void*)g,
      (__attribute__((address_space(3))) void*)l, 16, 0, 0);
}

// r4 skeleton (4 waves x 64 cols, wf[8][4] resident, 2 barriers/iter) with the
// staging converted to async global_load_lds:
//  - As is fp32 single-buffer [32][256] (32 KB). DMA writes it linearly per
//    row; the conflict swizzle lives on the SOURCE address (m173 pattern):
//    dest 16B-chunk c' of row r holds logical chunk c' ^ (2*(r&7))
//    -> K-loop reads 32B granule phys_g = (4ks+quad) ^ (row&7), same as r4.
//  - f2bf conversion moves to fragment-read time (identical values/output).
//  - rows >= 25 clamp the SOURCE row to 24 (in-bounds, finite); their
//    contributions are masked downstream (softmax j<NJ, stores nr<NJ).
//  - read depth: 8 KB in flight per wave (was 128 B with nf[8] register
//    prefetch) -> breaks the 1.7 TB/s read-queue ceiling measured in r4.
// Hazards (2 barriers): As DMA(4) -> K-read across barB; As K-read -> DMA(4)
// across barA; S3 write(2) -> read(6) across barA, reread fenced by barB(prev);
// Ps write(6) -> read(8) across barB; Yt wave-private; stores drain at next barA.
__global__ __launch_bounds__(BLOCK, 2)
void geo_gcn_fused(const float* __restrict__ x,
                   const float* __restrict__ w,
                   float* __restrict__ out)
{
  __shared__ float Asf[32][256];    // 32768 B, fp32, source-swizzled
  __shared__ short Ps[32][40];      //  2560 B
  __shared__ float S3[32][36];      //  4608 B
  __shared__ short Yt[4][64][32];   // 16384 B, swizzled  -> 56320 B total

  const int tid  = threadIdx.x;
  const int wv   = tid >> 6;        // 0..3, owns cols [64*wv, 64*wv+64)
  const int lane = tid & 63;
  const int quad = lane >> 4;
  const int l16  = lane & 15;

  // ---- persistent W fragments: wf[ks][td][j] = W[ks*32+quad*8+j][wv*64+td*16+l16]
  s16x8 wf[8][4];
  {
    const int ncol = wv * 64 + l16;
#pragma unroll
    for (int ks = 0; ks < 8; ++ks)
#pragma unroll
      for (int td = 0; td < 4; ++td) {
        const float* wp = w + (size_t)(ks * 32 + quad * 8) * DEPTH + ncol + td * 16;
#pragma unroll
        for (int j = 0; j < 8; ++j)
          wf[ks][td][j] = f2bf(wp[(size_t)j * DEPTH]);
      }
  }

  const int tm_s = wv >> 1;         // s3 tile (tm_s, tn_s) per wave
  const int tn_s = wv & 1;

  // ---- prologue: DMA element blockIdx.x into Asf ----
  {
    const float* xe = x + (size_t)blockIdx.x * DEPTH;
#pragma unroll
    for (int j = 0; j < 8; ++j) {
      const int r    = wv * 8 + j;
      const int nrow = (r < NJ) ? r : (NJ - 1);
      const float* src = xe + (size_t)nrow * BATCH * DEPTH
                            + ((lane ^ (2 * (r & 7))) << 2);
      dma16(src, &Asf[r][0]);
    }
  }
  __syncthreads();

  for (int ib = 0; ib < ITERS; ++ib) {
    const int b = blockIdx.x + GRID * ib;

    f32x4 sacc = (f32x4){0.f, 0.f, 0.f, 0.f};
    f32x4 yacc[2][4];
#pragma unroll
    for (int i = 0; i < 2; ++i)
#pragma unroll
      for (int j = 0; j < 4; ++j) yacc[i][j] = (f32x4){0.f, 0.f, 0.f, 0.f};

    // ---- [1] K loop: 8 x K=32; fp32 swizzled reads + f2bf -> 9 MFMAs ----
#pragma unroll
    for (int ks = 0; ks < 8; ++ks) {
      const int g0 = (((4 * ks + quad) ^ (l16 & 7)) << 3);   // float offset
      f32x4 ra = *(const f32x4*)&Asf[l16][g0];
      f32x4 rb = *(const f32x4*)&Asf[l16][g0 + 4];
      f32x4 rc = *(const f32x4*)&Asf[16 + l16][g0];          // (16+l16)&7 == l16&7
      f32x4 rd = *(const f32x4*)&Asf[16 + l16][g0 + 4];
      s16x8 a0, a1;
#pragma unroll
      for (int j = 0; j < 4; ++j) {
        a0[j] = f2bf(ra[j]); a0[4 + j] = f2bf(rb[j]);
        a1[j] = f2bf(rc[j]); a1[4 + j] = f2bf(rd[j]);
      }
      sacc = MFMA(tm_s ? a1 : a0, tn_s ? a1 : a0, sacc);
#pragma unroll
      for (int td = 0; td < 4; ++td) {
        yacc[0][td] = MFMA(a0, wf[ks][td], yacc[0][td]);
        yacc[1][td] = MFMA(a1, wf[ks][td], yacc[1][td]);
      }
    }

    // ---- [2] s3 -> S3 (pitch 36: 2-way max) ----
#pragma unroll
    for (int r = 0; r < 4; ++r)
      S3[tm_s * 16 + quad * 4 + r][tn_s * 16 + l16] = sacc[r];
    __syncthreads();   // [3] barA: all Asf reads done; prev stores aged by K loop

    // ---- [4] issue next element's DMA (async, zero dest regs) ----
    if (ib + 1 < ITERS) {
      const float* xe = x + (size_t)(b + GRID) * DEPTH;
#pragma unroll
      for (int j = 0; j < 8; ++j) {
        const int r    = wv * 8 + j;
        const int nrow = (r < NJ) ? r : (NJ - 1);
        const float* src = xe + (size_t)nrow * BATCH * DEPTH
                              + ((lane ^ (2 * (r & 7))) << 2);
        dma16(src, &Asf[r][0]);
      }
    }

    // ---- [5] Y (C-layout) -> Yt, phys_chunk = logical ^ ((d>>1)&3) ----
#pragma unroll
    for (int tm = 0; tm < 2; ++tm)
#pragma unroll
      for (int td = 0; td < 4; ++td) {
        s16x4 hy;
#pragma unroll
        for (int r = 0; r < 4; ++r) hy[r] = f2bf(yacc[tm][td][r]);
        const int pc = (tm * 2 + (quad >> 1)) ^ ((l16 >> 1) & 3);
        *(s16x4*)&Yt[wv][td * 16 + l16][pc * 8 + (quad & 1) * 4] = hy;
      }

    // ---- [6] wave-parallel softmax: 8 lanes/row over 32 rows ----
    {
      const int row = tid >> 3, c8 = tid & 7;
      float v[4]; float mx = -3.0e38f;
#pragma unroll
      for (int i = 0; i < 4; ++i) {
        const int j = c8 + 8 * i;
        v[i] = (j < NJ) ? S3[row][j] : -3.0e38f;
        mx = fmaxf(mx, v[i]);
      }
      mx = fmaxf(mx, __shfl_xor(mx, 1));
      mx = fmaxf(mx, __shfl_xor(mx, 2));
      mx = fmaxf(mx, __shfl_xor(mx, 4));
      float e[4]; float sum = 0.f;
#pragma unroll
      for (int i = 0; i < 4; ++i) {
        const int j = c8 + 8 * i;
        e[i] = (j < NJ) ? __expf(v[i] - mx) : 0.f;
        sum += e[i];
      }
      sum += __shfl_xor(sum, 1);
      sum += __shfl_xor(sum, 2);
      sum += __shfl_xor(sum, 4);
      const float rinv = 1.0f / sum;
#pragma unroll
      for (int i = 0; i < 4; ++i)
        Ps[row][c8 + 8 * i] = f2bf(e[i] * rinv);   // cols >= NJ get exact 0
    }
    __syncthreads();   // [7] barB: Ps ready; DMA drained (aged by [5][6])

    // ---- [8] out_strip = P @ Y_strip; stores last, drain at next barA ----
    s16x8 pf0 = *(const s16x8*)&Ps[l16][quad * 8];
    s16x8 pf1 = *(const s16x8*)&Ps[16 + l16][quad * 8];
    const f32x4 z4 = (f32x4){0.f, 0.f, 0.f, 0.f};
    float* ob = out + (size_t)b * NJ * DEPTH + wv * 64 + l16;
#pragma unroll
    for (int td = 0; td < 4; ++td) {
      const int pr = quad ^ ((l16 >> 1) & 3);    // swizzled Yt read
      s16x8 yb = *(const s16x8*)&Yt[wv][td * 16 + l16][pr * 8];
      f32x4 o0 = MFMA(pf0, yb, z4);
      f32x4 o1 = MFMA(pf1, yb, z4);
#pragma unroll
      for (int r = 0; r < 4; ++r) {
        ob[(size_t)(quad * 4 + r) * DEPTH + td * 16] = o0[r];   // rows 0..15
        const int nr = 16 + quad * 4 + r;                       // rows 16..24
        if (nr < NJ) ob[(size_t)nr * DEPTH + td * 16] = o1[r];
      }
    }
  }
}

extern "C" void kernel_launch(void* const* d_in, const int* in_sizes, int n_in,
                              void* d_out, int out_size, void* d_ws, size_t ws_size,
                              hipStream_t stream) {
  (void)in_sizes; (void)n_in; (void)out_size; (void)d_ws; (void)ws_size;
  const float* x = (const float*)d_in[0];
  const float* w = (const float*)d_in[1];
  float* out = (float*)d_out;
  geo_gcn_fused<<<dim3(GRID), dim3(BLOCK), 0, stream>>>(x, w, out);
}